// Round 7
// baseline (186.263 us; speedup 1.0000x reference)
//
#include <hip/hip_runtime.h>
#include <stdint.h>

#define BB 8
#define NN 2048
#define CC 64
#define KK 32
#define DK 16
#define RADIUSF 0.2f
#define EPSF 1e-8f
#define BN_EPSF 1e-5f

typedef unsigned long long u64;
typedef unsigned int u32;

// --- fp32 helpers matching the reference's arithmetic ---
// sum of squares: elementwise square (rounded) then sequential reduce — no FMA
__device__ __forceinline__ float refsq3(float a, float b, float c) {
  return __fadd_rn(__fadd_rn(__fmul_rn(a, a), __fmul_rn(b, b)), __fmul_rn(c, c));
}
// einsum dot: BLAS/Eigen/XLA style acc = fma(a_k, b_k, acc), k ascending
__device__ __forceinline__ float refdot3(float ax, float ay, float az,
                                         float bx, float by, float bz) {
  return __builtin_fmaf(az, bz, __builtin_fmaf(ay, by, __fmul_rn(ax, bx)));
}
__device__ __forceinline__ float refdist(float sx, float sy, float dt) {
  float d2 = __fsub_rn(__fadd_rn(sx, sy), __fmul_rn(2.0f, dt));
  d2 = fmaxf(d2, 0.0f);
  return d2 > 0.0f ? __fsqrt_rn(d2) : 0.0f;
}

// ---------------------------------------------------------------------------
// Kernel 0: pack coords + exact ref-rounded sq-norm into float4 (x,y,z,sn).
// ---------------------------------------------------------------------------
__global__ __launch_bounds__(256) void pack_kernel(const float* __restrict__ coords,
                                                   float4* __restrict__ P) {
  int t = blockIdx.x * 256 + threadIdx.x;   // 0..16383
  float x = coords[t * 3 + 0], y = coords[t * 3 + 1], z = coords[t * 3 + 2];
  P[t] = make_float4(x, y, z, refsq3(x, y, z));
}

// ---------------------------------------------------------------------------
// Kernel 1: G[b][n][c] = inv[c]*(W_f[c,:]·feats[b,:,n]) + shift[c]
// ---------------------------------------------------------------------------
__global__ __launch_bounds__(256) void gfeat_kernel(
    const float* __restrict__ feats, const float* __restrict__ conv_w,
    const float* __restrict__ gamma, const float* __restrict__ beta,
    const float* __restrict__ mean, const float* __restrict__ var,
    float* __restrict__ G) {
  __shared__ float wlds[64 * 65];
  for (int e = threadIdx.x; e < 4096; e += 256) {
    int c = e >> 6, cp = e & 63;
    wlds[c * 65 + cp] = conv_w[c * (CC + 3) + 3 + cp];
  }
  __syncthreads();
  int t = blockIdx.x * 256 + threadIdx.x;   // t = m*64 + c
  int c = t & 63;
  int m = t >> 6;                            // b*N + n
  int b = m >> 11;
  int n = m & (NN - 1);
  float inv = __fdiv_rn(gamma[c], __fsqrt_rn(__fadd_rn(var[c], BN_EPSF)));
  float shift = __fsub_rn(beta[c], __fmul_rn(mean[c], inv));
  const float* f = feats + (size_t)b * CC * NN + n;   // stride NN over c'
  float acc = 0.f;
#pragma unroll
  for (int cp = 0; cp < CC; ++cp) acc = fmaf(wlds[c * 65 + cp], f[(size_t)cp * NN], acc);
  G[t] = fmaf(inv, acc, shift);
}

// ---------------------------------------------------------------------------
// Kernel 2: exact KNN-SET via byte-radix select (order-free: downstream is
// permutation-invariant). One wave per query; 4 independent waves per block
// (histograms wave-private -> NO block barriers; same-wave DS ops are
// in-order, __threadfence_block stops compiler reordering only).
// No launch_bounds occupancy arg: the (256,8)/(256,4) variants capped VGPR
// at 32/64 and spilled du[] (WRITE_SIZE 75-200MB of scratch evictions).
// Histogram reads transposed (bin = lane + 64t, stride-1 across lanes =
// conflict-free) with counts packed in one u64 -> single 6-step wave scan.
// ---------------------------------------------------------------------------
__global__ __launch_bounds__(256) void knn_kernel(const float4* __restrict__ P,
                                                  int* __restrict__ idx_out) {
  __shared__ u32 hist[4 * 1028];            // per-wave 1028 u32 (4 reps × 257)
  const int tid = threadIdx.x;
  const int lane = tid & 63;
  const int wv = tid >> 6;
  const int pid = blockIdx.x * 4 + wv;      // b*N + i
  const int b = pid >> 11;
  const int i = pid & (NN - 1);
  const float4* Pb = P + ((size_t)b << 11);
  float4 q = Pb[i];
  u32* h = hist + wv * 1028;
  u32* hr = h + (lane & 3) * 257;           // this lane's replica

  u32 du[32];
#pragma unroll
  for (int c = 0; c < 32; ++c) {
    int j = (c << 6) | lane;
    float4 p = Pb[j];
    float dt = refdot3(q.x, q.y, q.z, p.x, p.y, p.z);
    du[c] = __float_as_uint(refdist(q.w, p.w, dt));
  }

  u32 prefix = 0;
  u32 k_need = KK;
#pragma unroll
  for (int ps = 0; ps < 4; ++ps) {
    const int sh = 24 - 8 * ps;
    // zero this wave's histogram (wave-private; no cross-wave hazard)
    for (int w = lane; w < 1028; w += 64) h[w] = 0;
    __threadfence_block();
    // accumulate
#pragma unroll
    for (int c = 0; c < 32; ++c) {
      bool act = (ps == 0) || ((du[c] >> (sh + 8)) == prefix);
      if (act) atomicAdd(&hr[(du[c] >> sh) & 0xFF], 1u);
    }
    __threadfence_block();
    // transposed per-lane totals: bins {lane, 64+lane, 128+lane, 192+lane}
    u32 c0 = h[lane] + h[257 + lane] + h[514 + lane] + h[771 + lane];
    u32 c1 = h[64 + lane] + h[321 + lane] + h[578 + lane] + h[835 + lane];
    u32 c2 = h[128 + lane] + h[385 + lane] + h[642 + lane] + h[899 + lane];
    u32 c3 = h[192 + lane] + h[449 + lane] + h[706 + lane] + h[963 + lane];
    // pack 4 counts (<=2048 each, sums <=2048 fit 16 bits) into one u64
    u64 v = (u64)c0 | ((u64)c1 << 16) | ((u64)c2 << 32) | ((u64)c3 << 48);
    // inclusive wave scan (per-field simultaneously; no cross-field carry)
#pragma unroll
    for (int s = 1; s < 64; s <<= 1) {
      u64 o = __shfl_up(v, s, 64);
      if (lane >= s) v += o;
    }
    u64 tot = __shfl(v, 63);                 // per-field wave totals
    u32 T0 = (u32)(tot & 0xFFFF);
    u32 T1 = (u32)((tot >> 16) & 0xFFFF);
    u32 T2 = (u32)((tot >> 32) & 0xFFFF);
    u32 i0 = (u32)(v & 0xFFFF);
    u32 i1 = (u32)((v >> 16) & 0xFFFF);
    u32 i2 = (u32)((v >> 32) & 0xFFFF);
    u32 i3 = (u32)((v >> 48) & 0xFFFF);
    // global inclusive/exclusive cumulative per owned bin; unique crossing
    u32 res = 0xFFFFFFFFu;
    {
      u32 Gi = i0, G = i0 - c0;
      if (G < k_need && k_need <= Gi) res = ((u32)lane << 12) | G;
    }
    {
      u32 Gi = T0 + i1, G = Gi - c1;
      if (G < k_need && k_need <= Gi) res = ((u32)(64 + lane) << 12) | G;
    }
    {
      u32 Gi = T0 + T1 + i2, G = Gi - c2;
      if (G < k_need && k_need <= Gi) res = ((u32)(128 + lane) << 12) | G;
    }
    {
      u32 Gi = T0 + T1 + T2 + i3, G = Gi - c3;
      if (G < k_need && k_need <= Gi) res = ((u32)(192 + lane) << 12) | G;
    }
#pragma unroll
    for (int s = 1; s < 64; s <<= 1) {
      u32 o = __shfl_xor(res, s);
      res = o < res ? o : res;
    }
    prefix = (prefix << 8) | ((res >> 12) & 0xFF);
    k_need -= (res & 0xFFF);
    __threadfence_block();   // order reads before next pass's zeroing
  }

  const u32 D = prefix;       // exact 32nd-smallest dist bits
  const u32 r = k_need;       // how many to take among du == D (>= 1)

  // collect du < D at prefix-scanned positions (order arbitrary)
  u32 cntL = 0;
#pragma unroll
  for (int c = 0; c < 32; ++c) cntL += (du[c] < D) ? 1u : 0u;
  u32 v2 = cntL;
#pragma unroll
  for (int s = 1; s < 64; s <<= 1) {
    u32 o = __shfl_up(v2, s, 64);
    if (lane >= s) v2 += o;
  }
  u32 pos = v2 - cntL;
  int* op = idx_out + (size_t)pid * KK;
#pragma unroll
  for (int c = 0; c < 32; ++c) {
    if (du[c] < D) { op[pos] = (c << 6) | lane; ++pos; }
  }
  // ties at D: take r smallest indices (c ascending, lane ascending)
  u32 rem = r;
#pragma unroll
  for (int c = 0; c < 32; ++c) {
    if (rem != 0) {
      u64 mask = __ballot(du[c] == D);
      while (mask != 0 && rem != 0) {
        int lw = (int)__ffsll((unsigned long long)mask) - 1;
        if (lane == lw) op[KK - rem] = (c << 6) | lw;
        --rem;
        mask &= mask - 1;
      }
    }
  }
}

// ---------------------------------------------------------------------------
// Kernel 3: density weights. 8 points per 256-thread block, 32 lanes/point.
// ---------------------------------------------------------------------------
__global__ __launch_bounds__(256) void density_kernel(const float* __restrict__ coords,
                                                      const int* __restrict__ idxb,
                                                      float* __restrict__ wbuf) {
  const int k = threadIdx.x & 31;
  const int sub = threadIdx.x >> 5;            // 0..7
  const int pid = blockIdx.x * 8 + sub;        // b*N + i
  const int b = pid >> 11;
  const float* cb = coords + (size_t)b * NN * 3;
  int j = idxb[(size_t)pid * KK + k];
  float nx = cb[j * 3 + 0], ny = cb[j * 3 + 1], nz = cb[j * 3 + 2];
  float sme = refsq3(nx, ny, nz);

  float d[32];
#pragma unroll
  for (int t = 0; t < 32; ++t) {
    float ox = __shfl(nx, t, 32);
    float oy = __shfl(ny, t, 32);
    float oz = __shfl(nz, t, 32);
    float so = refsq3(ox, oy, oz);
    float dt = refdot3(nx, ny, nz, ox, oy, oz);
    float dd = refdist(sme, so, dt);
    d[t] = (t == k) ? INFINITY : dd;   // eye mask
  }

  // sort 32 f32 ascending (values only; need the 16th smallest VALUE)
#pragma unroll
  for (int p = 1; p < 32; p <<= 1) {
#pragma unroll
    for (int kk = p; kk >= 1; kk >>= 1) {
#pragma unroll
      for (int jj = (kk & (p - 1)); jj + kk < 32; jj += 2 * kk) {
#pragma unroll
        for (int t = 0; t < kk; ++t) {
          if ((t + jj) / (2 * p) == (t + jj + kk) / (2 * p)) {
            float a = d[t + jj], b2 = d[t + jj + kk];
            float lo = fminf(a, b2);
            float hi = fmaxf(a, b2);
            d[t + jj] = lo;
            d[t + jj + kk] = hi;
          }
        }
      }
    }
  }

  float kth = d[DK - 1];
  float r1 = fmaxf(kth, EPSF);
  float raw = __fmul_rn(__fmul_rn(r1, r1), r1);
  float s = raw;
#pragma unroll
  for (int t = 1; t < 32; t <<= 1) s += __shfl_xor(s, t, 32);
  wbuf[(size_t)pid * KK + k] = raw / fmaxf(s, EPSF);
}

// ---------------------------------------------------------------------------
// Kernel 4: aggregation. One wave/point, lane = channel.
// ---------------------------------------------------------------------------
__global__ __launch_bounds__(256) void agg_kernel(
    const float* __restrict__ coords, const float* __restrict__ conv_w,
    const float* __restrict__ gamma, const float* __restrict__ var,
    const float* __restrict__ G, const int* __restrict__ idxb,
    const float* __restrict__ wbuf, float* __restrict__ out) {
  const int lane = threadIdx.x & 63;
  const int wv = threadIdx.x >> 6;
  const int pid = blockIdx.x * 4 + wv;   // b*N + i
  const int b = pid >> 11;
  const int i = pid & (NN - 1);
  const float* cb = coords + (size_t)b * NN * 3;

  float inv = __fdiv_rn(gamma[lane], __fsqrt_rn(__fadd_rn(var[lane], BN_EPSF)));
  float w0 = conv_w[lane * (CC + 3) + 0] * inv;
  float w1 = conv_w[lane * (CC + 3) + 1] * inv;
  float w2 = conv_w[lane * (CC + 3) + 2] * inv;

  float cx = cb[i * 3 + 0], cy = cb[i * 3 + 1], cz = cb[i * 3 + 2];
  float rx = 0.f, ry = 0.f, rz = 0.f, wk = 0.f;
  int jk = 0;
  if (lane < 32) {
    jk = idxb[(size_t)pid * KK + lane];
    rx = __fdiv_rn(__fsub_rn(cb[jk * 3 + 0], cx), RADIUSF);
    ry = __fdiv_rn(__fsub_rn(cb[jk * 3 + 1], cy), RADIUSF);
    rz = __fdiv_rn(__fsub_rn(cb[jk * 3 + 2], cz), RADIUSF);
    wk = wbuf[(size_t)pid * KK + lane];
  }

  float acc = 0.f;
#pragma unroll
  for (int k = 0; k < KK; ++k) {
    int j = __shfl(jk, k);
    float sx = __shfl(rx, k);
    float sy = __shfl(ry, k);
    float sz = __shfl(rz, k);
    float sw = __shfl(wk, k);
    float g = G[((size_t)(b * NN + j)) * 64 + lane];
    float y = fmaf(w2, sz, fmaf(w1, sy, fmaf(w0, sx, g)));
    y = fmaxf(y, 0.f);
    acc = fmaf(sw, y, acc);
  }
  out[((size_t)(b * 64 + lane)) * NN + i] = acc;
}

// ---------------------------------------------------------------------------
extern "C" void kernel_launch(void* const* d_in, const int* in_sizes, int n_in,
                              void* d_out, int out_size, void* d_ws, size_t ws_size,
                              hipStream_t stream) {
  const float* coords = (const float*)d_in[0];
  const float* feats  = (const float*)d_in[1];
  const float* conv_w = (const float*)d_in[2];
  const float* gamma  = (const float*)d_in[3];
  const float* beta   = (const float*)d_in[4];
  const float* mean   = (const float*)d_in[5];
  const float* var    = (const float*)d_in[6];
  float* out = (float*)d_out;

  int*   idxb = (int*)d_ws;                                          // 2 MB
  float* wbuf = (float*)((char*)d_ws + (size_t)2 * 1024 * 1024);     // 2 MB
  float* G    = (float*)((char*)d_ws + (size_t)4 * 1024 * 1024);     // 4 MB
  // P aliases the G region: knn consumes P before gfeat overwrites G.
  float4* P   = (float4*)G;                                          // 256 KB

  const int NPTS = BB * NN;   // 16384

  pack_kernel<<<NPTS / 256, 256, 0, stream>>>(coords, P);
  knn_kernel<<<NPTS / 4, 256, 0, stream>>>(P, idxb);
  gfeat_kernel<<<(NPTS * CC) / 256, 256, 0, stream>>>(feats, conv_w, gamma, beta,
                                                      mean, var, G);
  density_kernel<<<NPTS / 8, 256, 0, stream>>>(coords, idxb, wbuf);
  agg_kernel<<<NPTS / 4, 256, 0, stream>>>(coords, conv_w, gamma, var, G, idxb,
                                           wbuf, out);
}

// Round 8
// 164.174 us; speedup vs baseline: 1.1345x; 1.1345x over previous
//
#include <hip/hip_runtime.h>
#include <stdint.h>

#define BB 8
#define NN 2048
#define CC 64
#define KK 32
#define DK 16
#define RADIUSF 0.2f
#define EPSF 1e-8f
#define BN_EPSF 1e-5f

typedef unsigned long long u64;
typedef unsigned int u32;

// --- fp32 helpers matching the reference's arithmetic ---
// sum of squares: elementwise square (rounded) then sequential reduce — no FMA
__device__ __forceinline__ float refsq3(float a, float b, float c) {
  return __fadd_rn(__fadd_rn(__fmul_rn(a, a), __fmul_rn(b, b)), __fmul_rn(c, c));
}
// einsum dot: BLAS/Eigen/XLA style acc = fma(a_k, b_k, acc), k ascending
__device__ __forceinline__ float refdot3(float ax, float ay, float az,
                                         float bx, float by, float bz) {
  return __builtin_fmaf(az, bz, __builtin_fmaf(ay, by, __fmul_rn(ax, bx)));
}
__device__ __forceinline__ float refdist(float sx, float sy, float dt) {
  float d2 = __fsub_rn(__fadd_rn(sx, sy), __fmul_rn(2.0f, dt));
  d2 = fmaxf(d2, 0.0f);
  return d2 > 0.0f ? __fsqrt_rn(d2) : 0.0f;
}

// ---------------------------------------------------------------------------
// Kernel 0: pack coords + exact ref-rounded sq-norm into float4 (x,y,z,sn).
// ---------------------------------------------------------------------------
__global__ __launch_bounds__(256) void pack_kernel(const float* __restrict__ coords,
                                                   float4* __restrict__ P) {
  int t = blockIdx.x * 256 + threadIdx.x;   // 0..16383
  float x = coords[t * 3 + 0], y = coords[t * 3 + 1], z = coords[t * 3 + 2];
  P[t] = make_float4(x, y, z, refsq3(x, y, z));
}

// ---------------------------------------------------------------------------
// Kernel 1: G[b][n][c] = inv[c]*(W_f[c,:]·feats[b,:,n]) + shift[c]
// ---------------------------------------------------------------------------
__global__ __launch_bounds__(256) void gfeat_kernel(
    const float* __restrict__ feats, const float* __restrict__ conv_w,
    const float* __restrict__ gamma, const float* __restrict__ beta,
    const float* __restrict__ mean, const float* __restrict__ var,
    float* __restrict__ G) {
  __shared__ float wlds[64 * 65];
  for (int e = threadIdx.x; e < 4096; e += 256) {
    int c = e >> 6, cp = e & 63;
    wlds[c * 65 + cp] = conv_w[c * (CC + 3) + 3 + cp];
  }
  __syncthreads();
  int t = blockIdx.x * 256 + threadIdx.x;   // t = m*64 + c
  int c = t & 63;
  int m = t >> 6;                            // b*N + n
  int b = m >> 11;
  int n = m & (NN - 1);
  float inv = __fdiv_rn(gamma[c], __fsqrt_rn(__fadd_rn(var[c], BN_EPSF)));
  float shift = __fsub_rn(beta[c], __fmul_rn(mean[c], inv));
  const float* f = feats + (size_t)b * CC * NN + n;   // stride NN over c'
  float acc = 0.f;
#pragma unroll
  for (int cp = 0; cp < CC; ++cp) acc = fmaf(wlds[c * 65 + cp], f[(size_t)cp * NN], acc);
  G[t] = fmaf(inv, acc, shift);
}

// ---------------------------------------------------------------------------
// Kernel 2: exact KNN-SET via byte-radix select. TWO waves per query (each
// owns 1024 candidates, du[16] -> ~50 VGPR, no spill at the 64-cap), one
// shared per-query histogram; block = 4 waves = 2 queries. Occupancy is the
// lever: this kernel is latency-bound, and VGPR<=64 doubles waves/SIMD
// (r6: VGPR64+spill 113us > r7: VGPR88 no-spill 135us).
// Histogram reads transposed (stride-1 across lanes, conflict-free), counts
// packed in one u64 -> single 6-step wave scan. Tie-break exact: wave0's
// candidate indices all < wave1's, so wave0's ties fill first.
// ---------------------------------------------------------------------------
__global__ __launch_bounds__(256, 4) void knn_kernel(const float4* __restrict__ P,
                                                     int* __restrict__ idx_out) {
  __shared__ u32 hist[2 * 1028];   // per-query 1028 u32 (4 replicas × 257)
  __shared__ u32 comm[4];          // [s]: wave0 du<D total; [2+s]: wave0 ties
  const int tid = threadIdx.x;
  const int lane = tid & 63;
  const int wv = tid >> 6;
  const int s = wv >> 1;                    // query slot in block (0,1)
  const int wq = wv & 1;                    // candidate half (0,1)
  const int pid = blockIdx.x * 2 + s;       // b*N + i
  const int b = pid >> 11;
  const int i = pid & (NN - 1);
  const float4* Pb = P + ((size_t)b << 11);
  float4 q = Pb[i];
  u32* h = hist + s * 1028;
  u32* hr = h + (lane & 3) * 257;           // this lane's replica

  u32 du[16];
#pragma unroll
  for (int c = 0; c < 16; ++c) {
    int j = (wq << 10) | (c << 6) | lane;
    float4 p = Pb[j];
    float dt = refdot3(q.x, q.y, q.z, p.x, p.y, p.z);
    du[c] = __float_as_uint(refdist(q.w, p.w, dt));
  }

  u32 prefix = 0;
  u32 k_need = KK;
#pragma unroll
  for (int ps = 0; ps < 4; ++ps) {
    const int sh = 24 - 8 * ps;
    for (int w = tid; w < 2056; w += 256) hist[w] = 0;
    __syncthreads();
#pragma unroll
    for (int c = 0; c < 16; ++c) {
      bool act = (ps == 0) || ((du[c] >> (sh + 8)) == prefix);
      if (act) atomicAdd(&hr[(du[c] >> sh) & 0xFF], 1u);
    }
    __syncthreads();
    // transposed per-lane totals: bins {lane, 64+lane, 128+lane, 192+lane}
    u32 c0 = h[lane] + h[257 + lane] + h[514 + lane] + h[771 + lane];
    u32 c1 = h[64 + lane] + h[321 + lane] + h[578 + lane] + h[835 + lane];
    u32 c2 = h[128 + lane] + h[385 + lane] + h[642 + lane] + h[899 + lane];
    u32 c3 = h[192 + lane] + h[449 + lane] + h[706 + lane] + h[963 + lane];
    u64 v = (u64)c0 | ((u64)c1 << 16) | ((u64)c2 << 32) | ((u64)c3 << 48);
#pragma unroll
    for (int sft = 1; sft < 64; sft <<= 1) {
      u64 o = __shfl_up(v, sft, 64);
      if (lane >= sft) v += o;
    }
    u64 tot = __shfl(v, 63);                 // per-field wave totals
    u32 T0 = (u32)(tot & 0xFFFF);
    u32 T1 = (u32)((tot >> 16) & 0xFFFF);
    u32 T2 = (u32)((tot >> 32) & 0xFFFF);
    u32 i0 = (u32)(v & 0xFFFF);
    u32 i1 = (u32)((v >> 16) & 0xFFFF);
    u32 i2 = (u32)((v >> 32) & 0xFFFF);
    u32 i3 = (u32)((v >> 48) & 0xFFFF);
    u32 res = 0xFFFFFFFFu;
    {
      u32 Gi = i0, G = i0 - c0;
      if (G < k_need && k_need <= Gi) res = ((u32)lane << 12) | G;
    }
    {
      u32 Gi = T0 + i1, G = Gi - c1;
      if (G < k_need && k_need <= Gi) res = ((u32)(64 + lane) << 12) | G;
    }
    {
      u32 Gi = T0 + T1 + i2, G = Gi - c2;
      if (G < k_need && k_need <= Gi) res = ((u32)(128 + lane) << 12) | G;
    }
    {
      u32 Gi = T0 + T1 + T2 + i3, G = Gi - c3;
      if (G < k_need && k_need <= Gi) res = ((u32)(192 + lane) << 12) | G;
    }
#pragma unroll
    for (int sft = 1; sft < 64; sft <<= 1) {
      u32 o = __shfl_xor(res, sft);
      res = o < res ? o : res;
    }
    prefix = (prefix << 8) | ((res >> 12) & 0xFF);
    k_need -= (res & 0xFFF);
    __syncthreads();   // protect histogram reads before next pass's zeroing
  }

  const u32 D = prefix;       // exact 32nd-smallest dist bits
  const u32 r = k_need;       // how many to take among du == D (>= 1)

  // count du < D and ties per wave
  u32 cntL = 0;
#pragma unroll
  for (int c = 0; c < 16; ++c) cntL += (du[c] < D) ? 1u : 0u;
  u32 v2 = cntL;
#pragma unroll
  for (int sft = 1; sft < 64; sft <<= 1) {
    u32 o = __shfl_up(v2, sft, 64);
    if (lane >= sft) v2 += o;
  }
  u32 tieCnt = 0;
#pragma unroll
  for (int c = 0; c < 16; ++c) {
    u64 m = __ballot(du[c] == D);
    tieCnt += (u32)__popcll(m);
  }
  if (wq == 0 && lane == 63) comm[s] = v2;          // wave0 inclusive total du<D
  if (wq == 0 && lane == 0) comm[2 + s] = tieCnt;   // wave0 tie count
  __syncthreads();

  u32 pos = v2 - cntL + (wq ? comm[s] : 0);
  int* op = idx_out + (size_t)pid * KK;
#pragma unroll
  for (int c = 0; c < 16; ++c) {
    if (du[c] < D) { op[pos] = (wq << 10) | (c << 6) | lane; ++pos; }
  }
  // ties at D: r smallest indices overall = wave0's ties (ascending) first
  u32 t0 = comm[2 + s];
  u32 already = t0 < r ? t0 : r;
  u32 emit = (wq == 0) ? already : (r - already);
  u32 wpos = KK - r + (wq ? already : 0);
#pragma unroll
  for (int c = 0; c < 16; ++c) {
    if (emit != 0) {
      u64 mask = __ballot(du[c] == D);
      while (mask != 0 && emit != 0) {
        int lw = (int)__ffsll((unsigned long long)mask) - 1;
        if (lane == lw) op[wpos] = (wq << 10) | (c << 6) | lw;
        ++wpos;
        --emit;
        mask &= mask - 1;
      }
    }
  }
}

// ---------------------------------------------------------------------------
// Kernel 3: density weights. 8 points per 256-thread block, 32 lanes/point.
// ---------------------------------------------------------------------------
__global__ __launch_bounds__(256) void density_kernel(const float* __restrict__ coords,
                                                      const int* __restrict__ idxb,
                                                      float* __restrict__ wbuf) {
  const int k = threadIdx.x & 31;
  const int sub = threadIdx.x >> 5;            // 0..7
  const int pid = blockIdx.x * 8 + sub;        // b*N + i
  const int b = pid >> 11;
  const float* cb = coords + (size_t)b * NN * 3;
  int j = idxb[(size_t)pid * KK + k];
  float nx = cb[j * 3 + 0], ny = cb[j * 3 + 1], nz = cb[j * 3 + 2];
  float sme = refsq3(nx, ny, nz);

  float d[32];
#pragma unroll
  for (int t = 0; t < 32; ++t) {
    float ox = __shfl(nx, t, 32);
    float oy = __shfl(ny, t, 32);
    float oz = __shfl(nz, t, 32);
    float so = refsq3(ox, oy, oz);
    float dt = refdot3(nx, ny, nz, ox, oy, oz);
    float dd = refdist(sme, so, dt);
    d[t] = (t == k) ? INFINITY : dd;   // eye mask
  }

  // sort 32 f32 ascending (values only; need the 16th smallest VALUE)
#pragma unroll
  for (int p = 1; p < 32; p <<= 1) {
#pragma unroll
    for (int kk = p; kk >= 1; kk >>= 1) {
#pragma unroll
      for (int jj = (kk & (p - 1)); jj + kk < 32; jj += 2 * kk) {
#pragma unroll
        for (int t = 0; t < kk; ++t) {
          if ((t + jj) / (2 * p) == (t + jj + kk) / (2 * p)) {
            float a = d[t + jj], b2 = d[t + jj + kk];
            float lo = fminf(a, b2);
            float hi = fmaxf(a, b2);
            d[t + jj] = lo;
            d[t + jj + kk] = hi;
          }
        }
      }
    }
  }

  float kth = d[DK - 1];
  float r1 = fmaxf(kth, EPSF);
  float raw = __fmul_rn(__fmul_rn(r1, r1), r1);
  float s = raw;
#pragma unroll
  for (int t = 1; t < 32; t <<= 1) s += __shfl_xor(s, t, 32);
  wbuf[(size_t)pid * KK + k] = raw / fmaxf(s, EPSF);
}

// ---------------------------------------------------------------------------
// Kernel 4: aggregation. One wave/point, lane = channel.
// ---------------------------------------------------------------------------
__global__ __launch_bounds__(256) void agg_kernel(
    const float* __restrict__ coords, const float* __restrict__ conv_w,
    const float* __restrict__ gamma, const float* __restrict__ var,
    const float* __restrict__ G, const int* __restrict__ idxb,
    const float* __restrict__ wbuf, float* __restrict__ out) {
  const int lane = threadIdx.x & 63;
  const int wv = threadIdx.x >> 6;
  const int pid = blockIdx.x * 4 + wv;   // b*N + i
  const int b = pid >> 11;
  const int i = pid & (NN - 1);
  const float* cb = coords + (size_t)b * NN * 3;

  float inv = __fdiv_rn(gamma[lane], __fsqrt_rn(__fadd_rn(var[lane], BN_EPSF)));
  float w0 = conv_w[lane * (CC + 3) + 0] * inv;
  float w1 = conv_w[lane * (CC + 3) + 1] * inv;
  float w2 = conv_w[lane * (CC + 3) + 2] * inv;

  float cx = cb[i * 3 + 0], cy = cb[i * 3 + 1], cz = cb[i * 3 + 2];
  float rx = 0.f, ry = 0.f, rz = 0.f, wk = 0.f;
  int jk = 0;
  if (lane < 32) {
    jk = idxb[(size_t)pid * KK + lane];
    rx = __fdiv_rn(__fsub_rn(cb[jk * 3 + 0], cx), RADIUSF);
    ry = __fdiv_rn(__fsub_rn(cb[jk * 3 + 1], cy), RADIUSF);
    rz = __fdiv_rn(__fsub_rn(cb[jk * 3 + 2], cz), RADIUSF);
    wk = wbuf[(size_t)pid * KK + lane];
  }

  float acc = 0.f;
#pragma unroll
  for (int k = 0; k < KK; ++k) {
    int j = __shfl(jk, k);
    float sx = __shfl(rx, k);
    float sy = __shfl(ry, k);
    float sz = __shfl(rz, k);
    float sw = __shfl(wk, k);
    float g = G[((size_t)(b * NN + j)) * 64 + lane];
    float y = fmaf(w2, sz, fmaf(w1, sy, fmaf(w0, sx, g)));
    y = fmaxf(y, 0.f);
    acc = fmaf(sw, y, acc);
  }
  out[((size_t)(b * 64 + lane)) * NN + i] = acc;
}

// ---------------------------------------------------------------------------
extern "C" void kernel_launch(void* const* d_in, const int* in_sizes, int n_in,
                              void* d_out, int out_size, void* d_ws, size_t ws_size,
                              hipStream_t stream) {
  const float* coords = (const float*)d_in[0];
  const float* feats  = (const float*)d_in[1];
  const float* conv_w = (const float*)d_in[2];
  const float* gamma  = (const float*)d_in[3];
  const float* beta   = (const float*)d_in[4];
  const float* mean   = (const float*)d_in[5];
  const float* var    = (const float*)d_in[6];
  float* out = (float*)d_out;

  int*   idxb = (int*)d_ws;                                          // 2 MB
  float* wbuf = (float*)((char*)d_ws + (size_t)2 * 1024 * 1024);     // 2 MB
  float* G    = (float*)((char*)d_ws + (size_t)4 * 1024 * 1024);     // 4 MB
  // P aliases the G region: knn consumes P before gfeat overwrites G.
  float4* P   = (float4*)G;                                          // 256 KB

  const int NPTS = BB * NN;   // 16384

  pack_kernel<<<NPTS / 256, 256, 0, stream>>>(coords, P);
  knn_kernel<<<NPTS / 2, 256, 0, stream>>>(P, idxb);
  gfeat_kernel<<<(NPTS * CC) / 256, 256, 0, stream>>>(feats, conv_w, gamma, beta,
                                                      mean, var, G);
  density_kernel<<<NPTS / 8, 256, 0, stream>>>(coords, idxb, wbuf);
  agg_kernel<<<NPTS / 4, 256, 0, stream>>>(coords, conv_w, gamma, var, G, idxb,
                                           wbuf, out);
}

// Round 9
// 146.135 us; speedup vs baseline: 1.2746x; 1.1234x over previous
//
#include <hip/hip_runtime.h>
#include <stdint.h>

#define BB 8
#define NN 2048
#define CC 64
#define KK 32
#define DK 16
#define RADIUSF 0.2f
#define EPSF 1e-8f
#define BN_EPSF 1e-5f

typedef unsigned long long u64;
typedef unsigned int u32;

// --- fp32 helpers matching the reference's arithmetic ---
__device__ __forceinline__ float refsq3(float a, float b, float c) {
  return __fadd_rn(__fadd_rn(__fmul_rn(a, a), __fmul_rn(b, b)), __fmul_rn(c, c));
}
__device__ __forceinline__ float refdot3(float ax, float ay, float az,
                                         float bx, float by, float bz) {
  return __builtin_fmaf(az, bz, __builtin_fmaf(ay, by, __fmul_rn(ax, bx)));
}
__device__ __forceinline__ float refdist(float sx, float sy, float dt) {
  float d2 = __fsub_rn(__fadd_rn(sx, sy), __fmul_rn(2.0f, dt));
  d2 = fmaxf(d2, 0.0f);
  return d2 > 0.0f ? __fsqrt_rn(d2) : 0.0f;
}

// ---------------------------------------------------------------------------
// Kernel 0: pack coords + exact ref-rounded sq-norm into float4 (x,y,z,sn).
// ---------------------------------------------------------------------------
__global__ __launch_bounds__(256) void pack_kernel(const float* __restrict__ coords,
                                                   float4* __restrict__ P) {
  int t = blockIdx.x * 256 + threadIdx.x;   // 0..16383
  float x = coords[t * 3 + 0], y = coords[t * 3 + 1], z = coords[t * 3 + 2];
  P[t] = make_float4(x, y, z, refsq3(x, y, z));
}

// ---------------------------------------------------------------------------
// Kernel 1: G[b][n][c] = inv[c]*(W_f[c,:]·feats[b,:,n]) + shift[c]
// ---------------------------------------------------------------------------
__global__ __launch_bounds__(256) void gfeat_kernel(
    const float* __restrict__ feats, const float* __restrict__ conv_w,
    const float* __restrict__ gamma, const float* __restrict__ beta,
    const float* __restrict__ mean, const float* __restrict__ var,
    float* __restrict__ G) {
  __shared__ float wlds[64 * 65];
  for (int e = threadIdx.x; e < 4096; e += 256) {
    int c = e >> 6, cp = e & 63;
    wlds[c * 65 + cp] = conv_w[c * (CC + 3) + 3 + cp];
  }
  __syncthreads();
  int t = blockIdx.x * 256 + threadIdx.x;   // t = m*64 + c
  int c = t & 63;
  int m = t >> 6;                            // b*N + n
  int b = m >> 11;
  int n = m & (NN - 1);
  float inv = __fdiv_rn(gamma[c], __fsqrt_rn(__fadd_rn(var[c], BN_EPSF)));
  float shift = __fsub_rn(beta[c], __fmul_rn(mean[c], inv));
  const float* f = feats + (size_t)b * CC * NN + n;   // stride NN over c'
  float acc = 0.f;
#pragma unroll
  for (int cp = 0; cp < CC; ++cp) acc = fmaf(wlds[c * 65 + cp], f[(size_t)cp * NN], acc);
  G[t] = fmaf(inv, acc, shift);
}

// ---------------------------------------------------------------------------
// Kernel 2: exact KNN-SET via 3-pass 10-bit radix select, one wave per query,
// FULLY wave-private (zero block barriers; same-wave DS ops are in-order).
// d in [0, sqrt(3)] => du>>20 <= 1021, so pass 1 digit = du>>20 (1024 bins),
// passes 2/3 = bits [19:10], [9:0]. One reused 1024-bin histogram per wave,
// stored padded (bin b at word b + b/16): lane L's 16 bins sit at 17L+i,
// 17 coprime 32 -> conflict-free sum/locate reads. Fused dist+histogram loop.
// u32 du[32] + (256,4) 64-VGPR cap: fits, no spill (r6's spill was u64 keys).
// ---------------------------------------------------------------------------
__global__ __launch_bounds__(256, 4) void knn_kernel(const float4* __restrict__ P,
                                                     int* __restrict__ idx_out) {
  __shared__ u32 hist[4 * 1092];            // per-wave 1088 (1024 + 64 pad) + 4
  const int tid = threadIdx.x;
  const int lane = tid & 63;
  const int wv = tid >> 6;
  const int pid = blockIdx.x * 4 + wv;      // b*N + i
  const int b = pid >> 11;
  const int i = pid & (NN - 1);
  const float4* Pb = P + ((size_t)b << 11);
  float4 q = Pb[i];
  u32* h = hist + wv * 1092;

  // zero histogram (1088 = 17*64 words)
#pragma unroll
  for (int w = 0; w < 17; ++w) h[w * 64 + lane] = 0;

  // fused distance + pass-1 histogram (digit = du>>20)
  u32 du[32];
#pragma unroll
  for (int c = 0; c < 32; ++c) {
    int j = (c << 6) | lane;
    float4 p = Pb[j];
    float dt = refdot3(q.x, q.y, q.z, p.x, p.y, p.z);
    du[c] = __float_as_uint(refdist(q.w, p.w, dt));
    u32 bin = du[c] >> 20;
    atomicAdd(&h[bin + (bin >> 4)], 1u);
  }

  u32 kneed = KK;
  u32 pref = 0;   // accumulated digit prefix
#pragma unroll
  for (int ps = 0; ps < 3; ++ps) {
    if (ps != 0) {
      const int sh = (ps == 1) ? 10 : 0;
      // re-zero + re-accumulate among prefix-matching candidates
#pragma unroll
      for (int w = 0; w < 17; ++w) h[w * 64 + lane] = 0;
#pragma unroll
      for (int c = 0; c < 32; ++c) {
        bool act = (du[c] >> (sh + 10)) == pref;
        if (act) {
          u32 bin = (du[c] >> sh) & 0x3FF;
          atomicAdd(&h[bin + (bin >> 4)], 1u);
        }
      }
    }
    // per-lane total of its 16 bins (addresses 17*lane + i, conflict-free)
    u32 s = 0;
#pragma unroll
    for (int t2 = 0; t2 < 16; ++t2) s += h[17 * lane + t2];
    // inclusive wave scan
    u32 v = s;
#pragma unroll
    for (int sft = 1; sft < 64; sft <<= 1) {
      u32 o = __shfl_up(v, sft, 64);
      if (lane >= sft) v += o;
    }
    u32 excl = v - s;
    // locate crossing bin within the (unique) crossing lane
    u32 res = 0xFFFFFFFFu;
    if (excl < kneed && kneed <= v) {
      u32 run = excl, bin = 0, below = excl;
      bool found = false;
#pragma unroll
      for (int t2 = 0; t2 < 16; ++t2) {
        u32 cv = h[17 * lane + t2];
        bool hit = !found && (run + cv >= kneed);
        if (hit) { bin = (u32)(16 * lane + t2); below = run; found = true; }
        run += cv;
      }
      res = (bin << 12) | below;
    }
#pragma unroll
    for (int sft = 1; sft < 64; sft <<= 1) {
      u32 o = __shfl_xor(res, sft);
      res = o < res ? o : res;
    }
    pref = (pref << 10) | (res >> 12);
    kneed -= (res & 0xFFF);
  }

  const u32 D = pref;         // exact 32nd-smallest dist bits
  const u32 r = kneed;        // how many to take among du == D (>= 1)

  // emit du < D at prefix-scanned positions (order arbitrary; set exact)
  u32 cntL = 0;
#pragma unroll
  for (int c = 0; c < 32; ++c) cntL += (du[c] < D) ? 1u : 0u;
  u32 v2 = cntL;
#pragma unroll
  for (int sft = 1; sft < 64; sft <<= 1) {
    u32 o = __shfl_up(v2, sft, 64);
    if (lane >= sft) v2 += o;
  }
  u32 pos = v2 - cntL;
  int* op = idx_out + (size_t)pid * KK;
#pragma unroll
  for (int c = 0; c < 32; ++c) {
    if (du[c] < D) { op[pos] = (c << 6) | lane; ++pos; }
  }
  // ties at D: take r smallest indices (c ascending, lane ascending = j asc)
  u32 emit = r;
  u32 wpos = KK - r;
#pragma unroll
  for (int c = 0; c < 32; ++c) {
    if (emit != 0) {
      u64 m = __ballot(du[c] == D);
      u32 pc = (u32)__popcll(m);
      u32 rk = (u32)__popcll(m & ((1ull << lane) - 1ull));
      if ((du[c] == D) && rk < emit) op[wpos + rk] = (c << 6) | lane;
      u32 take = pc < emit ? pc : emit;
      wpos += take;
      emit -= take;
    }
  }
}

// ---------------------------------------------------------------------------
// Kernel 3: density weights. 8 points per 256-thread block, 32 lanes/point.
// ---------------------------------------------------------------------------
__global__ __launch_bounds__(256) void density_kernel(const float* __restrict__ coords,
                                                      const int* __restrict__ idxb,
                                                      float* __restrict__ wbuf) {
  const int k = threadIdx.x & 31;
  const int sub = threadIdx.x >> 5;            // 0..7
  const int pid = blockIdx.x * 8 + sub;        // b*N + i
  const int b = pid >> 11;
  const float* cb = coords + (size_t)b * NN * 3;
  int j = idxb[(size_t)pid * KK + k];
  float nx = cb[j * 3 + 0], ny = cb[j * 3 + 1], nz = cb[j * 3 + 2];
  float sme = refsq3(nx, ny, nz);

  float d[32];
#pragma unroll
  for (int t = 0; t < 32; ++t) {
    float ox = __shfl(nx, t, 32);
    float oy = __shfl(ny, t, 32);
    float oz = __shfl(nz, t, 32);
    float so = refsq3(ox, oy, oz);
    float dt = refdot3(nx, ny, nz, ox, oy, oz);
    float dd = refdist(sme, so, dt);
    d[t] = (t == k) ? INFINITY : dd;   // eye mask
  }

  // sort 32 f32 ascending (values only; need the 16th smallest VALUE)
#pragma unroll
  for (int p = 1; p < 32; p <<= 1) {
#pragma unroll
    for (int kk = p; kk >= 1; kk >>= 1) {
#pragma unroll
      for (int jj = (kk & (p - 1)); jj + kk < 32; jj += 2 * kk) {
#pragma unroll
        for (int t = 0; t < kk; ++t) {
          if ((t + jj) / (2 * p) == (t + jj + kk) / (2 * p)) {
            float a = d[t + jj], b2 = d[t + jj + kk];
            float lo = fminf(a, b2);
            float hi = fmaxf(a, b2);
            d[t + jj] = lo;
            d[t + jj + kk] = hi;
          }
        }
      }
    }
  }

  float kth = d[DK - 1];
  float r1 = fmaxf(kth, EPSF);
  float raw = __fmul_rn(__fmul_rn(r1, r1), r1);
  float s = raw;
#pragma unroll
  for (int t = 1; t < 32; t <<= 1) s += __shfl_xor(s, t, 32);
  wbuf[(size_t)pid * KK + k] = raw / fmaxf(s, EPSF);
}

// ---------------------------------------------------------------------------
// Kernel 4: aggregation. One wave/point, lane = channel.
// ---------------------------------------------------------------------------
__global__ __launch_bounds__(256) void agg_kernel(
    const float* __restrict__ coords, const float* __restrict__ conv_w,
    const float* __restrict__ gamma, const float* __restrict__ var,
    const float* __restrict__ G, const int* __restrict__ idxb,
    const float* __restrict__ wbuf, float* __restrict__ out) {
  const int lane = threadIdx.x & 63;
  const int wv = threadIdx.x >> 6;
  const int pid = blockIdx.x * 4 + wv;   // b*N + i
  const int b = pid >> 11;
  const int i = pid & (NN - 1);
  const float* cb = coords + (size_t)b * NN * 3;

  float inv = __fdiv_rn(gamma[lane], __fsqrt_rn(__fadd_rn(var[lane], BN_EPSF)));
  float w0 = conv_w[lane * (CC + 3) + 0] * inv;
  float w1 = conv_w[lane * (CC + 3) + 1] * inv;
  float w2 = conv_w[lane * (CC + 3) + 2] * inv;

  float cx = cb[i * 3 + 0], cy = cb[i * 3 + 1], cz = cb[i * 3 + 2];
  float rx = 0.f, ry = 0.f, rz = 0.f, wk = 0.f;
  int jk = 0;
  if (lane < 32) {
    jk = idxb[(size_t)pid * KK + lane];
    rx = __fdiv_rn(__fsub_rn(cb[jk * 3 + 0], cx), RADIUSF);
    ry = __fdiv_rn(__fsub_rn(cb[jk * 3 + 1], cy), RADIUSF);
    rz = __fdiv_rn(__fsub_rn(cb[jk * 3 + 2], cz), RADIUSF);
    wk = wbuf[(size_t)pid * KK + lane];
  }

  float acc = 0.f;
#pragma unroll
  for (int k = 0; k < KK; ++k) {
    int j = __shfl(jk, k);
    float sx = __shfl(rx, k);
    float sy = __shfl(ry, k);
    float sz = __shfl(rz, k);
    float sw = __shfl(wk, k);
    float g = G[((size_t)(b * NN + j)) * 64 + lane];
    float y = fmaf(w2, sz, fmaf(w1, sy, fmaf(w0, sx, g)));
    y = fmaxf(y, 0.f);
    acc = fmaf(sw, y, acc);
  }
  out[((size_t)(b * 64 + lane)) * NN + i] = acc;
}

// ---------------------------------------------------------------------------
extern "C" void kernel_launch(void* const* d_in, const int* in_sizes, int n_in,
                              void* d_out, int out_size, void* d_ws, size_t ws_size,
                              hipStream_t stream) {
  const float* coords = (const float*)d_in[0];
  const float* feats  = (const float*)d_in[1];
  const float* conv_w = (const float*)d_in[2];
  const float* gamma  = (const float*)d_in[3];
  const float* beta   = (const float*)d_in[4];
  const float* mean   = (const float*)d_in[5];
  const float* var    = (const float*)d_in[6];
  float* out = (float*)d_out;

  int*   idxb = (int*)d_ws;                                          // 2 MB
  float* wbuf = (float*)((char*)d_ws + (size_t)2 * 1024 * 1024);     // 2 MB
  float* G    = (float*)((char*)d_ws + (size_t)4 * 1024 * 1024);     // 4 MB
  // P aliases the G region: knn consumes P before gfeat overwrites G.
  float4* P   = (float4*)G;                                          // 256 KB

  const int NPTS = BB * NN;   // 16384

  pack_kernel<<<NPTS / 256, 256, 0, stream>>>(coords, P);
  knn_kernel<<<NPTS / 4, 256, 0, stream>>>(P, idxb);
  gfeat_kernel<<<(NPTS * CC) / 256, 256, 0, stream>>>(feats, conv_w, gamma, beta,
                                                      mean, var, G);
  density_kernel<<<NPTS / 8, 256, 0, stream>>>(coords, idxb, wbuf);
  agg_kernel<<<NPTS / 4, 256, 0, stream>>>(coords, conv_w, gamma, var, G, idxb,
                                           wbuf, out);
}

// Round 10
// 141.241 us; speedup vs baseline: 1.3188x; 1.0346x over previous
//
#include <hip/hip_runtime.h>
#include <stdint.h>

#define BB 8
#define NN 2048
#define CC 64
#define KK 32
#define DK 16
#define RADIUSF 0.2f
#define EPSF 1e-8f
#define BN_EPSF 1e-5f

typedef unsigned long long u64;
typedef unsigned int u32;

// --- fp32 helpers matching the reference's arithmetic ---
__device__ __forceinline__ float refsq3(float a, float b, float c) {
  return __fadd_rn(__fadd_rn(__fmul_rn(a, a), __fmul_rn(b, b)), __fmul_rn(c, c));
}
__device__ __forceinline__ float refdot3(float ax, float ay, float az,
                                         float bx, float by, float bz) {
  return __builtin_fmaf(az, bz, __builtin_fmaf(ay, by, __fmul_rn(ax, bx)));
}
__device__ __forceinline__ float refdist(float sx, float sy, float dt) {
  float d2 = __fsub_rn(__fadd_rn(sx, sy), __fmul_rn(2.0f, dt));
  d2 = fmaxf(d2, 0.0f);
  return d2 > 0.0f ? __fsqrt_rn(d2) : 0.0f;
}

// ---------------------------------------------------------------------------
// Kernel 0: pack coords + exact ref-rounded sq-norm into float4 (x,y,z,sn).
// ---------------------------------------------------------------------------
__global__ __launch_bounds__(256) void pack_kernel(const float* __restrict__ coords,
                                                   float4* __restrict__ P) {
  int t = blockIdx.x * 256 + threadIdx.x;   // 0..16383
  float x = coords[t * 3 + 0], y = coords[t * 3 + 1], z = coords[t * 3 + 2];
  P[t] = make_float4(x, y, z, refsq3(x, y, z));
}

// ---------------------------------------------------------------------------
// Kernel 1: G[b][n][c] = inv[c]*(W_f[c,:]·feats[b,:,n]) + shift[c]
// ---------------------------------------------------------------------------
__global__ __launch_bounds__(256) void gfeat_kernel(
    const float* __restrict__ feats, const float* __restrict__ conv_w,
    const float* __restrict__ gamma, const float* __restrict__ beta,
    const float* __restrict__ mean, const float* __restrict__ var,
    float* __restrict__ G) {
  __shared__ float wlds[64 * 65];
  for (int e = threadIdx.x; e < 4096; e += 256) {
    int c = e >> 6, cp = e & 63;
    wlds[c * 65 + cp] = conv_w[c * (CC + 3) + 3 + cp];
  }
  __syncthreads();
  int t = blockIdx.x * 256 + threadIdx.x;   // t = m*64 + c
  int c = t & 63;
  int m = t >> 6;                            // b*N + n
  int b = m >> 11;
  int n = m & (NN - 1);
  float inv = __fdiv_rn(gamma[c], __fsqrt_rn(__fadd_rn(var[c], BN_EPSF)));
  float shift = __fsub_rn(beta[c], __fmul_rn(mean[c], inv));
  const float* f = feats + (size_t)b * CC * NN + n;   // stride NN over c'
  float acc = 0.f;
#pragma unroll
  for (int cp = 0; cp < CC; ++cp) acc = fmaf(wlds[c * 65 + cp], f[(size_t)cp * NN], acc);
  G[t] = fmaf(inv, acc, shift);
}

// ---------------------------------------------------------------------------
// Kernel 2: exact KNN-SET via REGISTER-ONLY bitonic top-32. One wave/query.
// No LDS, no atomics, no barriers (r9 post-mortem: radix select was ~85%
// stall on LDS dependency chains; distance math is ~3us of real work).
//  1) lane-local Batcher sort of 32 u32 dist-bits (values only - emission
//     re-derives indices from du[], so no index tracking in the network)
//  2) 6 shfl_xor levels: m[e] = min(m[e], partner.m[31-e]) keeps the EXACT
//     lower-32 of the pair's union (bitonic lemma); 5-stage bitonic cleanup
//     re-sorts between levels; partners converge to identical multisets ->
//     after mask=32 all lanes hold the global 32 smallest values.
//  3) D = max of final array (no cleanup needed); r = 32 - #(du<D);
//     emit phase identical to r9 (passed; D/r/tie semantics unchanged).
// ---------------------------------------------------------------------------
__global__ __launch_bounds__(256) void knn_kernel(const float4* __restrict__ P,
                                                  int* __restrict__ idx_out) {
  const int lane = threadIdx.x & 63;
  const int wv = threadIdx.x >> 6;
  const int pid = blockIdx.x * 4 + wv;      // b*N + i
  const int b = pid >> 11;
  const int i = pid & (NN - 1);
  const float4* Pb = P + ((size_t)b << 11);
  float4 q = Pb[i];

  u32 du[32], m[32];
#pragma unroll
  for (int c = 0; c < 32; ++c) {
    int j = (c << 6) | lane;
    float4 p = Pb[j];
    float dt = refdot3(q.x, q.y, q.z, p.x, p.y, p.z);
    du[c] = __float_as_uint(refdist(q.w, p.w, dt));
    m[c] = du[c];
  }

  // 1) lane-local Batcher odd-even mergesort, ascending (static indices)
#pragma unroll
  for (int p = 1; p < 32; p <<= 1) {
#pragma unroll
    for (int k = p; k >= 1; k >>= 1) {
#pragma unroll
      for (int j = (k & (p - 1)); j + k < 32; j += 2 * k) {
#pragma unroll
        for (int t = 0; t < k; ++t) {
          if ((t + j) / (2 * p) == (t + j + k) / (2 * p)) {
            u32 a = m[t + j], bb = m[t + j + k];
            m[t + j] = a < bb ? a : bb;
            m[t + j + k] = a < bb ? bb : a;
          }
        }
      }
    }
  }

  // 2) cross-lane merge-keep-lower-32 tree (masks 1,2,4,8,16,32)
#pragma unroll
  for (int lvl = 0; lvl < 6; ++lvl) {
    const int mask = 1 << lvl;
    // paired exchange: slots (e, 31-e); both shfls read before any write
#pragma unroll
    for (int e = 0; e < 16; ++e) {
      u32 t1 = __shfl_xor(m[31 - e], mask);   // partner's upper for my lower
      u32 t2 = __shfl_xor(m[e], mask);        // partner's lower for my upper
      m[e] = m[e] < t1 ? m[e] : t1;
      m[31 - e] = m[31 - e] < t2 ? m[31 - e] : t2;
    }
    if (lvl < 5) {
      // bitonic cleanup -> ascending (5 static stages)
#pragma unroll
      for (int d = 16; d >= 1; d >>= 1) {
#pragma unroll
        for (int e = 0; e < 32; ++e) {
          if ((e & d) == 0) {
            u32 a = m[e], bb = m[e + d];
            m[e] = a < bb ? a : bb;
            m[e + d] = a < bb ? bb : a;
          }
        }
      }
    }
  }

  // 3) D = max of the final bitonic array (tree reduce in registers)
#pragma unroll
  for (int d = 16; d >= 1; d >>= 1) {
#pragma unroll
    for (int e = 0; e < 32; ++e) {
      if ((e & d) == 0) {
        u32 a = m[e], bb = m[e + d];
        m[e] = a > bb ? a : bb;
      }
    }
  }
  const u32 D = m[0];         // exact 32nd-smallest dist bits (wave-uniform)

  // emit du < D at prefix-scanned positions (order arbitrary; set exact)
  u32 cntL = 0;
#pragma unroll
  for (int c = 0; c < 32; ++c) cntL += (du[c] < D) ? 1u : 0u;
  u32 v2 = cntL;
#pragma unroll
  for (int sft = 1; sft < 64; sft <<= 1) {
    u32 o = __shfl_up(v2, sft, 64);
    if (lane >= sft) v2 += o;
  }
  const u32 r = KK - __shfl(v2, 63);   // ties to take at D (>= 1)
  u32 pos = v2 - cntL;
  int* op = idx_out + (size_t)pid * KK;
#pragma unroll
  for (int c = 0; c < 32; ++c) {
    if (du[c] < D) { op[pos] = (c << 6) | lane; ++pos; }
  }
  // ties at D: take r smallest indices (c ascending, lane ascending = j asc)
  u32 emit = r;
  u32 wpos = KK - r;
#pragma unroll
  for (int c = 0; c < 32; ++c) {
    if (emit != 0) {
      u64 mk = __ballot(du[c] == D);
      u32 pc = (u32)__popcll(mk);
      u32 rk = (u32)__popcll(mk & ((1ull << lane) - 1ull));
      if ((du[c] == D) && rk < emit) op[wpos + rk] = (c << 6) | lane;
      u32 take = pc < emit ? pc : emit;
      wpos += take;
      emit -= take;
    }
  }
}

// ---------------------------------------------------------------------------
// Kernel 3: density weights. 8 points per 256-thread block, 32 lanes/point.
// ---------------------------------------------------------------------------
__global__ __launch_bounds__(256) void density_kernel(const float* __restrict__ coords,
                                                      const int* __restrict__ idxb,
                                                      float* __restrict__ wbuf) {
  const int k = threadIdx.x & 31;
  const int sub = threadIdx.x >> 5;            // 0..7
  const int pid = blockIdx.x * 8 + sub;        // b*N + i
  const int b = pid >> 11;
  const float* cb = coords + (size_t)b * NN * 3;
  int j = idxb[(size_t)pid * KK + k];
  float nx = cb[j * 3 + 0], ny = cb[j * 3 + 1], nz = cb[j * 3 + 2];
  float sme = refsq3(nx, ny, nz);

  float d[32];
#pragma unroll
  for (int t = 0; t < 32; ++t) {
    float ox = __shfl(nx, t, 32);
    float oy = __shfl(ny, t, 32);
    float oz = __shfl(nz, t, 32);
    float so = refsq3(ox, oy, oz);
    float dt = refdot3(nx, ny, nz, ox, oy, oz);
    float dd = refdist(sme, so, dt);
    d[t] = (t == k) ? INFINITY : dd;   // eye mask
  }

  // sort 32 f32 ascending (values only; need the 16th smallest VALUE)
#pragma unroll
  for (int p = 1; p < 32; p <<= 1) {
#pragma unroll
    for (int kk = p; kk >= 1; kk >>= 1) {
#pragma unroll
      for (int jj = (kk & (p - 1)); jj + kk < 32; jj += 2 * kk) {
#pragma unroll
        for (int t = 0; t < kk; ++t) {
          if ((t + jj) / (2 * p) == (t + jj + kk) / (2 * p)) {
            float a = d[t + jj], b2 = d[t + jj + kk];
            float lo = fminf(a, b2);
            float hi = fmaxf(a, b2);
            d[t + jj] = lo;
            d[t + jj + kk] = hi;
          }
        }
      }
    }
  }

  float kth = d[DK - 1];
  float r1 = fmaxf(kth, EPSF);
  float raw = __fmul_rn(__fmul_rn(r1, r1), r1);
  float s = raw;
#pragma unroll
  for (int t = 1; t < 32; t <<= 1) s += __shfl_xor(s, t, 32);
  wbuf[(size_t)pid * KK + k] = raw / fmaxf(s, EPSF);
}

// ---------------------------------------------------------------------------
// Kernel 4: aggregation. One wave/point, lane = channel.
// ---------------------------------------------------------------------------
__global__ __launch_bounds__(256) void agg_kernel(
    const float* __restrict__ coords, const float* __restrict__ conv_w,
    const float* __restrict__ gamma, const float* __restrict__ var,
    const float* __restrict__ G, const int* __restrict__ idxb,
    const float* __restrict__ wbuf, float* __restrict__ out) {
  const int lane = threadIdx.x & 63;
  const int wv = threadIdx.x >> 6;
  const int pid = blockIdx.x * 4 + wv;   // b*N + i
  const int b = pid >> 11;
  const int i = pid & (NN - 1);
  const float* cb = coords + (size_t)b * NN * 3;

  float inv = __fdiv_rn(gamma[lane], __fsqrt_rn(__fadd_rn(var[lane], BN_EPSF)));
  float w0 = conv_w[lane * (CC + 3) + 0] * inv;
  float w1 = conv_w[lane * (CC + 3) + 1] * inv;
  float w2 = conv_w[lane * (CC + 3) + 2] * inv;

  float cx = cb[i * 3 + 0], cy = cb[i * 3 + 1], cz = cb[i * 3 + 2];
  float rx = 0.f, ry = 0.f, rz = 0.f, wk = 0.f;
  int jk = 0;
  if (lane < 32) {
    jk = idxb[(size_t)pid * KK + lane];
    rx = __fdiv_rn(__fsub_rn(cb[jk * 3 + 0], cx), RADIUSF);
    ry = __fdiv_rn(__fsub_rn(cb[jk * 3 + 1], cy), RADIUSF);
    rz = __fdiv_rn(__fsub_rn(cb[jk * 3 + 2], cz), RADIUSF);
    wk = wbuf[(size_t)pid * KK + lane];
  }

  float acc = 0.f;
#pragma unroll
  for (int k = 0; k < KK; ++k) {
    int j = __shfl(jk, k);
    float sx = __shfl(rx, k);
    float sy = __shfl(ry, k);
    float sz = __shfl(rz, k);
    float sw = __shfl(wk, k);
    float g = G[((size_t)(b * NN + j)) * 64 + lane];
    float y = fmaf(w2, sz, fmaf(w1, sy, fmaf(w0, sx, g)));
    y = fmaxf(y, 0.f);
    acc = fmaf(sw, y, acc);
  }
  out[((size_t)(b * 64 + lane)) * NN + i] = acc;
}

// ---------------------------------------------------------------------------
extern "C" void kernel_launch(void* const* d_in, const int* in_sizes, int n_in,
                              void* d_out, int out_size, void* d_ws, size_t ws_size,
                              hipStream_t stream) {
  const float* coords = (const float*)d_in[0];
  const float* feats  = (const float*)d_in[1];
  const float* conv_w = (const float*)d_in[2];
  const float* gamma  = (const float*)d_in[3];
  const float* beta   = (const float*)d_in[4];
  const float* mean   = (const float*)d_in[5];
  const float* var    = (const float*)d_in[6];
  float* out = (float*)d_out;

  int*   idxb = (int*)d_ws;                                          // 2 MB
  float* wbuf = (float*)((char*)d_ws + (size_t)2 * 1024 * 1024);     // 2 MB
  float* G    = (float*)((char*)d_ws + (size_t)4 * 1024 * 1024);     // 4 MB
  // P aliases the G region: knn consumes P before gfeat overwrites G.
  float4* P   = (float4*)G;                                          // 256 KB

  const int NPTS = BB * NN;   // 16384

  pack_kernel<<<NPTS / 256, 256, 0, stream>>>(coords, P);
  knn_kernel<<<NPTS / 4, 256, 0, stream>>>(P, idxb);
  gfeat_kernel<<<(NPTS * CC) / 256, 256, 0, stream>>>(feats, conv_w, gamma, beta,
                                                      mean, var, G);
  density_kernel<<<NPTS / 8, 256, 0, stream>>>(coords, idxb, wbuf);
  agg_kernel<<<NPTS / 4, 256, 0, stream>>>(coords, conv_w, gamma, var, G, idxb,
                                           wbuf, out);
}

// Round 11
// 128.224 us; speedup vs baseline: 1.4526x; 1.1015x over previous
//
#include <hip/hip_runtime.h>
#include <stdint.h>

#define BB 8
#define NN 2048
#define CC 64
#define KK 32
#define DK 16
#define RADIUSF 0.2f
#define EPSF 1e-8f
#define BN_EPSF 1e-5f

typedef unsigned long long u64;
typedef unsigned int u32;

// --- fp32 helpers matching the reference's arithmetic ---
__device__ __forceinline__ float refsq3(float a, float b, float c) {
  return __fadd_rn(__fadd_rn(__fmul_rn(a, a), __fmul_rn(b, b)), __fmul_rn(c, c));
}
__device__ __forceinline__ float refdot3(float ax, float ay, float az,
                                         float bx, float by, float bz) {
  return __builtin_fmaf(az, bz, __builtin_fmaf(ay, by, __fmul_rn(ax, bx)));
}
__device__ __forceinline__ float refdist(float sx, float sy, float dt) {
  float d2 = __fsub_rn(__fadd_rn(sx, sy), __fmul_rn(2.0f, dt));
  d2 = fmaxf(d2, 0.0f);
  return d2 > 0.0f ? __fsqrt_rn(d2) : 0.0f;
}

// cross-lane bitonic sort of one u32 per lane, ascending by lane index
#define WAVE_SORT64(V)                                                        \
  {                                                                           \
    _Pragma("unroll") for (int k_ = 2; k_ <= 64; k_ <<= 1) {                  \
      _Pragma("unroll") for (int j_ = k_ >> 1; j_ >= 1; j_ >>= 1) {           \
        u32 o_ = __shfl_xor(V, j_);                                           \
        bool keepmin_ = ((lane & k_) == 0) == ((lane & j_) == 0);             \
        u32 mn_ = V < o_ ? V : o_;                                            \
        u32 mx_ = V < o_ ? o_ : V;                                            \
        V = keepmin_ ? mn_ : mx_;                                             \
      }                                                                       \
    }                                                                         \
  }

// ---------------------------------------------------------------------------
// Kernel 0: pack coords + exact ref-rounded sq-norm into float4 (x,y,z,sn).
// ---------------------------------------------------------------------------
__global__ __launch_bounds__(256) void pack_kernel(const float* __restrict__ coords,
                                                   float4* __restrict__ P) {
  int t = blockIdx.x * 256 + threadIdx.x;   // 0..16383
  float x = coords[t * 3 + 0], y = coords[t * 3 + 1], z = coords[t * 3 + 2];
  P[t] = make_float4(x, y, z, refsq3(x, y, z));
}

// ---------------------------------------------------------------------------
// Kernel 1: G[b][n][c] = inv[c]*(W_f[c,:]·feats[b,:,n]) + shift[c]
// ---------------------------------------------------------------------------
__global__ __launch_bounds__(256) void gfeat_kernel(
    const float* __restrict__ feats, const float* __restrict__ conv_w,
    const float* __restrict__ gamma, const float* __restrict__ beta,
    const float* __restrict__ mean, const float* __restrict__ var,
    float* __restrict__ G) {
  __shared__ float wlds[64 * 65];
  for (int e = threadIdx.x; e < 4096; e += 256) {
    int c = e >> 6, cp = e & 63;
    wlds[c * 65 + cp] = conv_w[c * (CC + 3) + 3 + cp];
  }
  __syncthreads();
  int t = blockIdx.x * 256 + threadIdx.x;   // t = m*64 + c
  int c = t & 63;
  int m = t >> 6;                            // b*N + n
  int b = m >> 11;
  int n = m & (NN - 1);
  float inv = __fdiv_rn(gamma[c], __fsqrt_rn(__fadd_rn(var[c], BN_EPSF)));
  float shift = __fsub_rn(beta[c], __fmul_rn(mean[c], inv));
  const float* f = feats + (size_t)b * CC * NN + n;   // stride NN over c'
  float acc = 0.f;
#pragma unroll
  for (int cp = 0; cp < CC; ++cp) acc = fmaf(wlds[c * 65 + cp], f[(size_t)cp * NN], acc);
  G[t] = fmaf(inv, acc, shift);
}

// ---------------------------------------------------------------------------
// Kernel 2: exact KNN-SET via threshold prefilter + survivor select.
// One wave/query. r10 post-mortem: full bitonic top-32 was VALU-throughput
// bound (~3500 instr/wave, mostly 5x 80-CE cleanups). Here:
//  - track each lane's 2 smallest during the distance loop
//  - T = 32nd smallest of the 128-sample {2 smallest per lane}  (>= D,
//    since the 32nd of a subset >= the 32nd of the full multiset; tight
//    because the true top-32 spread ~1/lane, so nearly all are sampled)
//  - n = #{du <= T}; mainline (n <= 64): ballot-compact survivor VALUES to
//    a wave-private 64-slot LDS strip, one cross-lane sort-64 -> D = S[31]
//  - fallback (n > 64, ties/clustered data): exact 31-step bit-binary-search
//    for D (register-cheap, rare)
//  - emit phase identical to r9/r10 (proven): du<D via scan, ties via
//    ballot rank (c asc, lane asc = index asc)
// ---------------------------------------------------------------------------
__global__ __launch_bounds__(256) void knn_kernel(const float4* __restrict__ P,
                                                  int* __restrict__ idx_out) {
  __shared__ u32 surv[4 * 64];              // wave-private survivor strips
  const int lane = threadIdx.x & 63;
  const int wv = threadIdx.x >> 6;
  const int pid = blockIdx.x * 4 + wv;      // b*N + i
  const int b = pid >> 11;
  const int i = pid & (NN - 1);
  const float4* Pb = P + ((size_t)b << 11);
  float4 q = Pb[i];
  u32* sv = surv + wv * 64;
  const u64 lml = (1ull << lane) - 1ull;    // lanemask_lt

  u32 du[32];
  u32 m0 = 0xFFFFFFFFu, m1 = 0xFFFFFFFFu;   // lane's two smallest
#pragma unroll
  for (int c = 0; c < 32; ++c) {
    int j = (c << 6) | lane;
    float4 p = Pb[j];
    float dt = refdot3(q.x, q.y, q.z, p.x, p.y, p.z);
    u32 d = __float_as_uint(refdist(q.w, p.w, dt));
    du[c] = d;
    u32 hi2 = d > m0 ? d : m0;              // max(m0, d)
    m0 = d < m0 ? d : m0;
    m1 = hi2 < m1 ? hi2 : m1;
  }

  // sort the lane-minima (A) and lane-2nd-minima (B) across lanes
  u32 Av = m0, Bv = m1;
  WAVE_SORT64(Av);
  WAVE_SORT64(Bv);

  // T = rank-31 (0-based) element of A ∪ B via per-lane merge-rank:
  // posA(l) = l + #{B < A_l};  posB(l) = l + #{A <= B_l}  (stable merge)
  u32 lbB = 0;   // lower_bound: #B < Av
#pragma unroll
  for (int sft = 32; sft >= 1; sft >>= 1) {
    u32 np = lbB + sft;
    u32 val = __shfl(Bv, (int)(np - 1));
    if (val < Av) lbB = np;
  }
  u32 ubA = 0;   // upper_bound: #A <= Bv
#pragma unroll
  for (int sft = 32; sft >= 1; sft >>= 1) {
    u32 np = ubA + sft;
    u32 val = __shfl(Av, (int)(np - 1));
    if (val <= Bv) ubA = np;
  }
  u32 cand = 0;
  if (lane + lbB == 31) cand = Av;
  u32 candB = (lane + ubA == 31) ? Bv : 0;
  cand = cand > candB ? cand : candB;
#pragma unroll
  for (int sft = 1; sft < 64; sft <<= 1) {
    u32 o = __shfl_xor(cand, sft);
    cand = o > cand ? o : cand;
  }
  const u32 T = cand;                       // exact 32nd of the 128-sample

  // survivor count n = #{du <= T} (wave total)
  u32 cls = 0;
#pragma unroll
  for (int c = 0; c < 32; ++c) cls += (du[c] <= T) ? 1u : 0u;
  u32 ntot = cls;
#pragma unroll
  for (int sft = 1; sft < 64; sft <<= 1) ntot += __shfl_xor(ntot, sft);

  u32 D;
  if (ntot <= 64) {
    // compact survivor values into LDS (order arbitrary)
    u32 base = 0;
#pragma unroll
    for (int c = 0; c < 32; ++c) {
      u64 mk = __ballot(du[c] <= T);
      u32 rk = (u32)__popcll(mk & lml);
      if (du[c] <= T) sv[base + rk] = du[c];
      base += (u32)__popcll(mk);
    }
    u32 x = (lane < (int)ntot) ? sv[lane] : 0xFFFFFFFFu;
    WAVE_SORT64(x);
    D = __shfl(x, 31);                      // exact 32nd smallest overall
  } else {
    // exact bit-descent: D = smallest v with count(du < v') semantics
    u32 ans = 0;
#pragma unroll 1
    for (int bbit = 30; bbit >= 0; --bbit) {
      u32 t2 = ans | (1u << bbit);
      u32 c2 = 0;
#pragma unroll
      for (int c = 0; c < 32; ++c) c2 += (du[c] < t2) ? 1u : 0u;
#pragma unroll
      for (int sft = 1; sft < 64; sft <<= 1) c2 += __shfl_xor(c2, sft);
      if (c2 < KK) ans = t2;
    }
    D = ans;
  }

  // emit du < D at prefix-scanned positions (order arbitrary; set exact)
  u32 cntL = 0;
#pragma unroll
  for (int c = 0; c < 32; ++c) cntL += (du[c] < D) ? 1u : 0u;
  u32 v2 = cntL;
#pragma unroll
  for (int sft = 1; sft < 64; sft <<= 1) {
    u32 o = __shfl_up(v2, sft, 64);
    if (lane >= sft) v2 += o;
  }
  const u32 r = KK - __shfl(v2, 63);   // ties to take at D (>= 1)
  u32 pos = v2 - cntL;
  int* op = idx_out + (size_t)pid * KK;
#pragma unroll
  for (int c = 0; c < 32; ++c) {
    if (du[c] < D) { op[pos] = (c << 6) | lane; ++pos; }
  }
  // ties at D: take r smallest indices (c ascending, lane ascending = j asc)
  u32 emit = r;
  u32 wpos = KK - r;
#pragma unroll
  for (int c = 0; c < 32; ++c) {
    if (emit != 0) {
      u64 mk = __ballot(du[c] == D);
      u32 pc = (u32)__popcll(mk);
      u32 rk = (u32)__popcll(mk & lml);
      if ((du[c] == D) && rk < emit) op[wpos + rk] = (c << 6) | lane;
      u32 take = pc < emit ? pc : emit;
      wpos += take;
      emit -= take;
    }
  }
}

// ---------------------------------------------------------------------------
// Kernel 3: density weights. 8 points per 256-thread block, 32 lanes/point.
// ---------------------------------------------------------------------------
__global__ __launch_bounds__(256) void density_kernel(const float* __restrict__ coords,
                                                      const int* __restrict__ idxb,
                                                      float* __restrict__ wbuf) {
  const int k = threadIdx.x & 31;
  const int sub = threadIdx.x >> 5;            // 0..7
  const int pid = blockIdx.x * 8 + sub;        // b*N + i
  const int b = pid >> 11;
  const float* cb = coords + (size_t)b * NN * 3;
  int j = idxb[(size_t)pid * KK + k];
  float nx = cb[j * 3 + 0], ny = cb[j * 3 + 1], nz = cb[j * 3 + 2];
  float sme = refsq3(nx, ny, nz);

  float d[32];
#pragma unroll
  for (int t = 0; t < 32; ++t) {
    float ox = __shfl(nx, t, 32);
    float oy = __shfl(ny, t, 32);
    float oz = __shfl(nz, t, 32);
    float so = refsq3(ox, oy, oz);
    float dt = refdot3(nx, ny, nz, ox, oy, oz);
    float dd = refdist(sme, so, dt);
    d[t] = (t == k) ? INFINITY : dd;   // eye mask
  }

  // sort 32 f32 ascending (values only; need the 16th smallest VALUE)
#pragma unroll
  for (int p = 1; p < 32; p <<= 1) {
#pragma unroll
    for (int kk = p; kk >= 1; kk >>= 1) {
#pragma unroll
      for (int jj = (kk & (p - 1)); jj + kk < 32; jj += 2 * kk) {
#pragma unroll
        for (int t = 0; t < kk; ++t) {
          if ((t + jj) / (2 * p) == (t + jj + kk) / (2 * p)) {
            float a = d[t + jj], b2 = d[t + jj + kk];
            float lo = fminf(a, b2);
            float hi = fmaxf(a, b2);
            d[t + jj] = lo;
            d[t + jj + kk] = hi;
          }
        }
      }
    }
  }

  float kth = d[DK - 1];
  float r1 = fmaxf(kth, EPSF);
  float raw = __fmul_rn(__fmul_rn(r1, r1), r1);
  float s = raw;
#pragma unroll
  for (int t = 1; t < 32; t <<= 1) s += __shfl_xor(s, t, 32);
  wbuf[(size_t)pid * KK + k] = raw / fmaxf(s, EPSF);
}

// ---------------------------------------------------------------------------
// Kernel 4: aggregation. One wave/point, lane = channel.
// ---------------------------------------------------------------------------
__global__ __launch_bounds__(256) void agg_kernel(
    const float* __restrict__ coords, const float* __restrict__ conv_w,
    const float* __restrict__ gamma, const float* __restrict__ var,
    const float* __restrict__ G, const int* __restrict__ idxb,
    const float* __restrict__ wbuf, float* __restrict__ out) {
  const int lane = threadIdx.x & 63;
  const int wv = threadIdx.x >> 6;
  const int pid = blockIdx.x * 4 + wv;   // b*N + i
  const int b = pid >> 11;
  const int i = pid & (NN - 1);
  const float* cb = coords + (size_t)b * NN * 3;

  float inv = __fdiv_rn(gamma[lane], __fsqrt_rn(__fadd_rn(var[lane], BN_EPSF)));
  float w0 = conv_w[lane * (CC + 3) + 0] * inv;
  float w1 = conv_w[lane * (CC + 3) + 1] * inv;
  float w2 = conv_w[lane * (CC + 3) + 2] * inv;

  float cx = cb[i * 3 + 0], cy = cb[i * 3 + 1], cz = cb[i * 3 + 2];
  float rx = 0.f, ry = 0.f, rz = 0.f, wk = 0.f;
  int jk = 0;
  if (lane < 32) {
    jk = idxb[(size_t)pid * KK + lane];
    rx = __fdiv_rn(__fsub_rn(cb[jk * 3 + 0], cx), RADIUSF);
    ry = __fdiv_rn(__fsub_rn(cb[jk * 3 + 1], cy), RADIUSF);
    rz = __fdiv_rn(__fsub_rn(cb[jk * 3 + 2], cz), RADIUSF);
    wk = wbuf[(size_t)pid * KK + lane];
  }

  float acc = 0.f;
#pragma unroll
  for (int k = 0; k < KK; ++k) {
    int j = __shfl(jk, k);
    float sx = __shfl(rx, k);
    float sy = __shfl(ry, k);
    float sz = __shfl(rz, k);
    float sw = __shfl(wk, k);
    float g = G[((size_t)(b * NN + j)) * 64 + lane];
    float y = fmaf(w2, sz, fmaf(w1, sy, fmaf(w0, sx, g)));
    y = fmaxf(y, 0.f);
    acc = fmaf(sw, y, acc);
  }
  out[((size_t)(b * 64 + lane)) * NN + i] = acc;
}

// ---------------------------------------------------------------------------
extern "C" void kernel_launch(void* const* d_in, const int* in_sizes, int n_in,
                              void* d_out, int out_size, void* d_ws, size_t ws_size,
                              hipStream_t stream) {
  const float* coords = (const float*)d_in[0];
  const float* feats  = (const float*)d_in[1];
  const float* conv_w = (const float*)d_in[2];
  const float* gamma  = (const float*)d_in[3];
  const float* beta   = (const float*)d_in[4];
  const float* mean   = (const float*)d_in[5];
  const float* var    = (const float*)d_in[6];
  float* out = (float*)d_out;

  int*   idxb = (int*)d_ws;                                          // 2 MB
  float* wbuf = (float*)((char*)d_ws + (size_t)2 * 1024 * 1024);     // 2 MB
  float* G    = (float*)((char*)d_ws + (size_t)4 * 1024 * 1024);     // 4 MB
  // P aliases the G region: knn consumes P before gfeat overwrites G.
  float4* P   = (float4*)G;                                          // 256 KB

  const int NPTS = BB * NN;   // 16384

  pack_kernel<<<NPTS / 256, 256, 0, stream>>>(coords, P);
  knn_kernel<<<NPTS / 4, 256, 0, stream>>>(P, idxb);
  gfeat_kernel<<<(NPTS * CC) / 256, 256, 0, stream>>>(feats, conv_w, gamma, beta,
                                                      mean, var, G);
  density_kernel<<<NPTS / 8, 256, 0, stream>>>(coords, idxb, wbuf);
  agg_kernel<<<NPTS / 4, 256, 0, stream>>>(coords, conv_w, gamma, var, G, idxb,
                                           wbuf, out);
}

// Round 12
// 112.832 us; speedup vs baseline: 1.6508x; 1.1364x over previous
//
#include <hip/hip_runtime.h>
#include <stdint.h>

#define BB 8
#define NN 2048
#define CC 64
#define KK 32
#define DK 16
#define RADIUSF 0.2f
#define EPSF 1e-8f
#define BN_EPSF 1e-5f

typedef unsigned long long u64;
typedef unsigned int u32;

// --- fp32 helpers matching the reference's arithmetic ---
__device__ __forceinline__ float refsq3(float a, float b, float c) {
  return __fadd_rn(__fadd_rn(__fmul_rn(a, a), __fmul_rn(b, b)), __fmul_rn(c, c));
}
__device__ __forceinline__ float refdot3(float ax, float ay, float az,
                                         float bx, float by, float bz) {
  return __builtin_fmaf(az, bz, __builtin_fmaf(ay, by, __fmul_rn(ax, bx)));
}
__device__ __forceinline__ float refdist(float sx, float sy, float dt) {
  float d2 = __fsub_rn(__fadd_rn(sx, sy), __fmul_rn(2.0f, dt));
  d2 = fmaxf(d2, 0.0f);
  return d2 > 0.0f ? __fsqrt_rn(d2) : 0.0f;
}

// cross-lane bitonic sort of one u32 per lane, ascending by lane index
#define WAVE_SORT64(V)                                                        \
  {                                                                           \
    _Pragma("unroll") for (int k_ = 2; k_ <= 64; k_ <<= 1) {                  \
      _Pragma("unroll") for (int j_ = k_ >> 1; j_ >= 1; j_ >>= 1) {           \
        u32 o_ = __shfl_xor(V, j_);                                           \
        bool keepmin_ = ((lane & k_) == 0) == ((lane & j_) == 0);             \
        u32 mn_ = V < o_ ? V : o_;                                            \
        u32 mx_ = V < o_ ? o_ : V;                                            \
        V = keepmin_ ? mn_ : mx_;                                             \
      }                                                                       \
    }                                                                         \
  }

// ---------------------------------------------------------------------------
// Kernel 0: pack coords + exact ref-rounded sq-norm into float4 (x,y,z,sn).
// ---------------------------------------------------------------------------
__global__ __launch_bounds__(256) void pack_kernel(const float* __restrict__ coords,
                                                   float4* __restrict__ P) {
  int t = blockIdx.x * 256 + threadIdx.x;   // 0..16383
  float x = coords[t * 3 + 0], y = coords[t * 3 + 1], z = coords[t * 3 + 2];
  P[t] = make_float4(x, y, z, refsq3(x, y, z));
}

// ---------------------------------------------------------------------------
// Kernel 1: G[b][n][c] = inv[c]*(W_f[c,:]·feats[b,:,n]) + shift[c]
// ---------------------------------------------------------------------------
__global__ __launch_bounds__(256) void gfeat_kernel(
    const float* __restrict__ feats, const float* __restrict__ conv_w,
    const float* __restrict__ gamma, const float* __restrict__ beta,
    const float* __restrict__ mean, const float* __restrict__ var,
    float* __restrict__ G) {
  __shared__ float wlds[64 * 65];
  for (int e = threadIdx.x; e < 4096; e += 256) {
    int c = e >> 6, cp = e & 63;
    wlds[c * 65 + cp] = conv_w[c * (CC + 3) + 3 + cp];
  }
  __syncthreads();
  int t = blockIdx.x * 256 + threadIdx.x;   // t = m*64 + c
  int c = t & 63;
  int m = t >> 6;                            // b*N + n
  int b = m >> 11;
  int n = m & (NN - 1);
  float inv = __fdiv_rn(gamma[c], __fsqrt_rn(__fadd_rn(var[c], BN_EPSF)));
  float shift = __fsub_rn(beta[c], __fmul_rn(mean[c], inv));
  const float* f = feats + (size_t)b * CC * NN + n;   // stride NN over c'
  float acc = 0.f;
#pragma unroll
  for (int cp = 0; cp < CC; ++cp) acc = fmaf(wlds[c * 65 + cp], f[(size_t)cp * NN], acc);
  G[t] = fmaf(inv, acc, shift);
}

// ---------------------------------------------------------------------------
// Kernel 2: exact KNN-SET, threshold prefilter + survivor select, one
// wave/query. r12: T = A[31] where A = sorted lane-minima.
// THEOREM: A[31] >= D (D = 32nd-smallest overall). Proof: #{values < D}
// <= 31, so at most 31 lanes contain a value < D, so at most 31 lane-minima
// are < D, so the 32nd-smallest lane-min >= D. Removes r11's second-minimum
// tracking, second sort-64, and 12-step merge-rank (~30% of machinery, -8
// VGPR of live state -> aim under the >64-VGPR occupancy cliff).
// Survivors n = #{du <= T} ~ 40-50; n<=64 mainline: ballot-compact values
// to LDS strip, one sort-64 -> D = S[31]. n>64 fallback: exact bit-descent.
// Emit identical to r9-r11 (proven): du<D via scan, ties via ballot rank.
// ---------------------------------------------------------------------------
__global__ __launch_bounds__(256) void knn_kernel(const float4* __restrict__ P,
                                                  int* __restrict__ idx_out) {
  __shared__ u32 surv[4 * 64];              // wave-private survivor strips
  const int lane = threadIdx.x & 63;
  const int wv = threadIdx.x >> 6;
  const int pid = blockIdx.x * 4 + wv;      // b*N + i
  const int b = pid >> 11;
  const int i = pid & (NN - 1);
  const float4* Pb = P + ((size_t)b << 11);
  float4 q = Pb[i];
  u32* sv = surv + wv * 64;
  const u64 lml = (1ull << lane) - 1ull;    // lanemask_lt

  u32 du[32];
  u32 m0 = 0xFFFFFFFFu;                     // lane minimum
#pragma unroll
  for (int c = 0; c < 32; ++c) {
    int j = (c << 6) | lane;
    float4 p = Pb[j];
    float dt = refdot3(q.x, q.y, q.z, p.x, p.y, p.z);
    u32 d = __float_as_uint(refdist(q.w, p.w, dt));
    du[c] = d;
    m0 = d < m0 ? d : m0;
  }

  // T = 32nd-smallest lane-minimum (>= D by the theorem above)
  u32 Av = m0;
  WAVE_SORT64(Av);
  const u32 T = __shfl(Av, 31);

  // survivor count n = #{du <= T} (wave total)
  u32 cls = 0;
#pragma unroll
  for (int c = 0; c < 32; ++c) cls += (du[c] <= T) ? 1u : 0u;
  u32 ntot = cls;
#pragma unroll
  for (int sft = 1; sft < 64; sft <<= 1) ntot += __shfl_xor(ntot, sft);

  u32 D;
  if (ntot <= 64) {
    // compact survivor values into LDS (order arbitrary)
    u32 base = 0;
#pragma unroll
    for (int c = 0; c < 32; ++c) {
      u64 mk = __ballot(du[c] <= T);
      u32 rk = (u32)__popcll(mk & lml);
      if (du[c] <= T) sv[base + rk] = du[c];
      base += (u32)__popcll(mk);
    }
    u32 x = (lane < (int)ntot) ? sv[lane] : 0xFFFFFFFFu;
    WAVE_SORT64(x);
    D = __shfl(x, 31);                      // exact 32nd smallest overall
  } else {
    // exact bit-descent fallback (rare): largest ans with #{du < ans} < 32
    u32 ans = 0;
#pragma unroll 1
    for (int bbit = 30; bbit >= 0; --bbit) {
      u32 t2 = ans | (1u << bbit);
      u32 c2 = 0;
#pragma unroll
      for (int c = 0; c < 32; ++c) c2 += (du[c] < t2) ? 1u : 0u;
#pragma unroll
      for (int sft = 1; sft < 64; sft <<= 1) c2 += __shfl_xor(c2, sft);
      if (c2 < KK) ans = t2;
    }
    D = ans;
  }

  // emit du < D at prefix-scanned positions (order arbitrary; set exact)
  u32 cntL = 0;
#pragma unroll
  for (int c = 0; c < 32; ++c) cntL += (du[c] < D) ? 1u : 0u;
  u32 v2 = cntL;
#pragma unroll
  for (int sft = 1; sft < 64; sft <<= 1) {
    u32 o = __shfl_up(v2, sft, 64);
    if (lane >= sft) v2 += o;
  }
  const u32 r = KK - __shfl(v2, 63);   // ties to take at D (>= 1)
  u32 pos = v2 - cntL;
  int* op = idx_out + (size_t)pid * KK;
#pragma unroll
  for (int c = 0; c < 32; ++c) {
    if (du[c] < D) { op[pos] = (c << 6) | lane; ++pos; }
  }
  // ties at D: take r smallest indices (c ascending, lane ascending = j asc)
  u32 emit = r;
  u32 wpos = KK - r;
#pragma unroll
  for (int c = 0; c < 32; ++c) {
    if (emit != 0) {
      u64 mk = __ballot(du[c] == D);
      u32 pc = (u32)__popcll(mk);
      u32 rk = (u32)__popcll(mk & lml);
      if ((du[c] == D) && rk < emit) op[wpos + rk] = (c << 6) | lane;
      u32 take = pc < emit ? pc : emit;
      wpos += take;
      emit -= take;
    }
  }
}

// ---------------------------------------------------------------------------
// Kernel 3: density weights. 8 points per 256-thread block, 32 lanes/point.
// ---------------------------------------------------------------------------
__global__ __launch_bounds__(256) void density_kernel(const float* __restrict__ coords,
                                                      const int* __restrict__ idxb,
                                                      float* __restrict__ wbuf) {
  const int k = threadIdx.x & 31;
  const int sub = threadIdx.x >> 5;            // 0..7
  const int pid = blockIdx.x * 8 + sub;        // b*N + i
  const int b = pid >> 11;
  const float* cb = coords + (size_t)b * NN * 3;
  int j = idxb[(size_t)pid * KK + k];
  float nx = cb[j * 3 + 0], ny = cb[j * 3 + 1], nz = cb[j * 3 + 2];
  float sme = refsq3(nx, ny, nz);

  float d[32];
#pragma unroll
  for (int t = 0; t < 32; ++t) {
    float ox = __shfl(nx, t, 32);
    float oy = __shfl(ny, t, 32);
    float oz = __shfl(nz, t, 32);
    float so = refsq3(ox, oy, oz);
    float dt = refdot3(nx, ny, nz, ox, oy, oz);
    float dd = refdist(sme, so, dt);
    d[t] = (t == k) ? INFINITY : dd;   // eye mask
  }

  // sort 32 f32 ascending (values only; need the 16th smallest VALUE)
#pragma unroll
  for (int p = 1; p < 32; p <<= 1) {
#pragma unroll
    for (int kk = p; kk >= 1; kk >>= 1) {
#pragma unroll
      for (int jj = (kk & (p - 1)); jj + kk < 32; jj += 2 * kk) {
#pragma unroll
        for (int t = 0; t < kk; ++t) {
          if ((t + jj) / (2 * p) == (t + jj + kk) / (2 * p)) {
            float a = d[t + jj], b2 = d[t + jj + kk];
            float lo = fminf(a, b2);
            float hi = fmaxf(a, b2);
            d[t + jj] = lo;
            d[t + jj + kk] = hi;
          }
        }
      }
    }
  }

  float kth = d[DK - 1];
  float r1 = fmaxf(kth, EPSF);
  float raw = __fmul_rn(__fmul_rn(r1, r1), r1);
  float s = raw;
#pragma unroll
  for (int t = 1; t < 32; t <<= 1) s += __shfl_xor(s, t, 32);
  wbuf[(size_t)pid * KK + k] = raw / fmaxf(s, EPSF);
}

// ---------------------------------------------------------------------------
// Kernel 4: aggregation. One wave/point, lane = channel.
// ---------------------------------------------------------------------------
__global__ __launch_bounds__(256) void agg_kernel(
    const float* __restrict__ coords, const float* __restrict__ conv_w,
    const float* __restrict__ gamma, const float* __restrict__ var,
    const float* __restrict__ G, const int* __restrict__ idxb,
    const float* __restrict__ wbuf, float* __restrict__ out) {
  const int lane = threadIdx.x & 63;
  const int wv = threadIdx.x >> 6;
  const int pid = blockIdx.x * 4 + wv;   // b*N + i
  const int b = pid >> 11;
  const int i = pid & (NN - 1);
  const float* cb = coords + (size_t)b * NN * 3;

  float inv = __fdiv_rn(gamma[lane], __fsqrt_rn(__fadd_rn(var[lane], BN_EPSF)));
  float w0 = conv_w[lane * (CC + 3) + 0] * inv;
  float w1 = conv_w[lane * (CC + 3) + 1] * inv;
  float w2 = conv_w[lane * (CC + 3) + 2] * inv;

  float cx = cb[i * 3 + 0], cy = cb[i * 3 + 1], cz = cb[i * 3 + 2];
  float rx = 0.f, ry = 0.f, rz = 0.f, wk = 0.f;
  int jk = 0;
  if (lane < 32) {
    jk = idxb[(size_t)pid * KK + lane];
    rx = __fdiv_rn(__fsub_rn(cb[jk * 3 + 0], cx), RADIUSF);
    ry = __fdiv_rn(__fsub_rn(cb[jk * 3 + 1], cy), RADIUSF);
    rz = __fdiv_rn(__fsub_rn(cb[jk * 3 + 2], cz), RADIUSF);
    wk = wbuf[(size_t)pid * KK + lane];
  }

  float acc = 0.f;
#pragma unroll
  for (int k = 0; k < KK; ++k) {
    int j = __shfl(jk, k);
    float sx = __shfl(rx, k);
    float sy = __shfl(ry, k);
    float sz = __shfl(rz, k);
    float sw = __shfl(wk, k);
    float g = G[((size_t)(b * NN + j)) * 64 + lane];
    float y = fmaf(w2, sz, fmaf(w1, sy, fmaf(w0, sx, g)));
    y = fmaxf(y, 0.f);
    acc = fmaf(sw, y, acc);
  }
  out[((size_t)(b * 64 + lane)) * NN + i] = acc;
}

// ---------------------------------------------------------------------------
extern "C" void kernel_launch(void* const* d_in, const int* in_sizes, int n_in,
                              void* d_out, int out_size, void* d_ws, size_t ws_size,
                              hipStream_t stream) {
  const float* coords = (const float*)d_in[0];
  const float* feats  = (const float*)d_in[1];
  const float* conv_w = (const float*)d_in[2];
  const float* gamma  = (const float*)d_in[3];
  const float* beta   = (const float*)d_in[4];
  const float* mean   = (const float*)d_in[5];
  const float* var    = (const float*)d_in[6];
  float* out = (float*)d_out;

  int*   idxb = (int*)d_ws;                                          // 2 MB
  float* wbuf = (float*)((char*)d_ws + (size_t)2 * 1024 * 1024);     // 2 MB
  float* G    = (float*)((char*)d_ws + (size_t)4 * 1024 * 1024);     // 4 MB
  // P aliases the G region: knn consumes P before gfeat overwrites G.
  float4* P   = (float4*)G;                                          // 256 KB

  const int NPTS = BB * NN;   // 16384

  pack_kernel<<<NPTS / 256, 256, 0, stream>>>(coords, P);
  knn_kernel<<<NPTS / 4, 256, 0, stream>>>(P, idxb);
  gfeat_kernel<<<(NPTS * CC) / 256, 256, 0, stream>>>(feats, conv_w, gamma, beta,
                                                      mean, var, G);
  density_kernel<<<NPTS / 8, 256, 0, stream>>>(coords, idxb, wbuf);
  agg_kernel<<<NPTS / 4, 256, 0, stream>>>(coords, conv_w, gamma, var, G, idxb,
                                           wbuf, out);
}